// Round 4
// baseline (3256.775 us; speedup 1.0000x reference)
//
#include <hip/hip_runtime.h>

// ---------------------------------------------------------------------------
// SchNet-style GNN on MI355X — R4.
// N=50000, E=1600000, H=128, F=64, G=50, L=3, NG=256.
// R4: the edge filter MLP W(d) is tabulated (4096-entry fp32 LUT per layer,
//     linear interp) — k_edge is now pure gather/lerp/scatter, no MFMA.
//     Edges bucket-sorted by dst>>6; k_edge = one block per 64-node bucket,
//     accumulating into an LDS tile with ds_add_f32 -> zero global atomics.
// Node GEMMs unchanged (bf16 MFMA, fused per layer).
// ---------------------------------------------------------------------------

typedef short bf16x8 __attribute__((ext_vector_type(8)));
typedef float floatx4 __attribute__((ext_vector_type(4)));

#define HCH 128
#define FCH 64
#define GCH 50
#define LN  3
#define TBL 4096
#define DMAX 8.6603f     // pos in [0,5)^3 -> d <= 5*sqrt(3)

#define MFMA(a, b, c) __builtin_amdgcn_mfma_f32_16x16x32_bf16((a), (b), (c), 0, 0, 0)

__device__ __forceinline__ unsigned short f2bf(float x) {
    unsigned int u = __float_as_uint(x);
    unsigned int r = (u + 0x7FFFu + ((u >> 16) & 1u)) >> 16;
    return (unsigned short)r;
}

__device__ __forceinline__ unsigned pk2bf(float lo, float hi) {
    unsigned ulo = __float_as_uint(lo) + 0x8000u;
    unsigned uhi = __float_as_uint(hi) + 0x8000u;
    return __builtin_amdgcn_perm(uhi, ulo, 0x07060302u);
}

__device__ __forceinline__ float sspf(float x) {
    float t = __expf(-fabsf(x));
    float l = __logf(1.f + t);
    return fmaxf(x, 0.f) + l - 0.69314718056f;
}

// ---------------------------------------------------------------------------
// frag fill for node-side MFMA weights (B-fragment order)
// ---------------------------------------------------------------------------
__device__ __forceinline__ void fill_frag(const float* __restrict__ src,
                                          short* __restrict__ dst,
                                          int K, int F, int Ksrc,
                                          int tid, int nthr)
{
    int kc = K >> 5;
    int total = (F >> 4) * kc * 512;
    for (int i = tid; i < total; i += nthr) {
        int j = i & 7;
        int lane = (i >> 3) & 63;
        int rest = i >> 9;
        int kk = rest % kc;
        int nt = rest / kc;
        int k = kk * 32 + ((lane >> 4) << 3) + j;
        int f = nt * 16 + (lane & 15);
        float v = (k < Ksrc) ? src[k * F + f] : 0.f;
        dst[i] = (short)f2bf(v);
    }
}

__global__ void k_prep(const float* __restrict__ l1w, const float* __restrict__ l2w,
                       const float* __restrict__ lw,  const float* __restrict__ ow1,
                       short* __restrict__ l1wp, short* __restrict__ l2wp,
                       short* __restrict__ lwp,  short* __restrict__ ow1p)
{
    int tid = blockIdx.x * blockDim.x + threadIdx.x;
    int nthr = gridDim.x * blockDim.x;
    for (int l = 0; l < LN; l++) {
        fill_frag(l1w + l * HCH * FCH, l1wp + l * 8192, 128, 64, 128, tid, nthr);
        fill_frag(l2w + l * FCH * HCH, l2wp + l * 8192, 64, 128, 64, tid, nthr);
        fill_frag(lw  + l * HCH * HCH, lwp  + l * 16384, 128, 128, 128, tid, nthr);
    }
    fill_frag(ow1, ow1p, 128, 64, 128, tid, nthr);
}

// ---------------------------------------------------------------------------
// Build W(d) lookup table: Wtab[l][k][f] = (ssp(ea(d_k)@mw1+b1)@mw2+b2)[f]
// Exact fp32 at grid points; edge kernel lerps between rows.
// ---------------------------------------------------------------------------
__global__ __launch_bounds__(256) void k_wtab(
    const float* __restrict__ mw1, const float* __restrict__ mb1,
    const float* __restrict__ mw2, const float* __restrict__ mb2,
    float* __restrict__ Wtab)
{
    int gid = blockIdx.x * 256 + threadIdx.x;
    if (gid >= LN * TBL) return;
    int l = gid / TBL, k = gid % TBL;
    float d = (float)k * (DMAX / (float)(TBL - 1));
    const float step = 10.f / 49.f;
    const float coeff = -0.5f / (step * step);

    float t1[64];
    const float* b1 = mb1 + l * FCH;
#pragma unroll
    for (int f = 0; f < 64; f++) t1[f] = b1[f];
    const float* w1 = mw1 + l * GCH * FCH;
    for (int g = 0; g < GCH; g++) {
        float u = d - (float)g * step;
        float s = __expf(coeff * u * u);
#pragma unroll
        for (int f = 0; f < 64; f++) t1[f] += s * w1[g * 64 + f];
    }
    float acc[64];
    const float* b2 = mb2 + l * FCH;
#pragma unroll
    for (int f = 0; f < 64; f++) acc[f] = b2[f];
    const float* w2 = mw2 + l * FCH * FCH;
    for (int g = 0; g < 64; g++) {
        float s = sspf(t1[g]);
#pragma unroll
        for (int f = 0; f < 64; f++) acc[f] += s * w2[g * 64 + f];
    }
    float* o = Wtab + ((size_t)l * TBL + k) * 64;
#pragma unroll
    for (int f = 0; f < 64; f++) o[f] = acc[f];
}

// ---------------------------------------------------------------------------
// Bucket sort by dst>>6: hist -> scan -> scatter (fused geometry, 16B payload)
// ---------------------------------------------------------------------------
__global__ void k_hist(const int* __restrict__ ei, int* __restrict__ hist, int E)
{
    int e = blockIdx.x * blockDim.x + threadIdx.x;
    if (e < E) atomicAdd(&hist[ei[E + e] >> 6], 1);
}

__global__ __launch_bounds__(1024) void k_scan(const int* __restrict__ hist,
                                               int* __restrict__ cursor,
                                               int* __restrict__ bstart, int nbk)
{
    __shared__ int part[1024];
    int t = threadIdx.x;
    int v = (t < nbk) ? hist[t] : 0;
    part[t] = v;
    __syncthreads();
    for (int off = 1; off < 1024; off <<= 1) {
        int u = (t >= off) ? part[t - off] : 0;
        __syncthreads();
        part[t] += u;
        __syncthreads();
    }
    int excl = part[t] - v;
    if (t < nbk) { cursor[t] = excl; bstart[t] = excl; }
    if (t == 1023) bstart[nbk] = part[1023];
}

__global__ void k_scatter2(const int* __restrict__ ei, const float* __restrict__ pos,
                           int* __restrict__ cursor, int4* __restrict__ edata, int E)
{
    int e = blockIdx.x * blockDim.x + threadIdx.x;
    if (e >= E) return;
    int s = ei[e], d2 = ei[E + e];
    float dx = pos[s * 3 + 0] - pos[d2 * 3 + 0];
    float dy = pos[s * 3 + 1] - pos[d2 * 3 + 1];
    float dz = pos[s * 3 + 2] - pos[d2 * 3 + 2];
    float dist = sqrtf(dx * dx + dy * dy + dz * dz);
    float C = 0.5f * (__cosf(dist * 0.31415926535897932f) + 1.f);
    int p = atomicAdd(&cursor[d2 >> 6], 1);
    edata[p] = make_int4(s, d2, __float_as_int(dist), __float_as_int(C));
}

// ---------------------------------------------------------------------------
// k_node0: h = emb[z]; xj = h @ l1w[0]
// ---------------------------------------------------------------------------
__global__ __launch_bounds__(256) void k_node0(const int* __restrict__ z,
    const float* __restrict__ emb, const short* __restrict__ l1wp0,
    float* __restrict__ h, float* __restrict__ xj, int N)
{
    __shared__ __align__(16) short A3[8192];
    __shared__ int zL[64];
    int t = threadIdx.x, lane = t & 63, w = t >> 6;
    int n0 = blockIdx.x * 64;
    if (t < 64) { int n = n0 + t; zL[t] = (n < N) ? z[n] : 0; }
    __syncthreads();
#pragma unroll
    for (int m = 0; m < 16; m++) {
        int ii = lane + 64 * m;
        int rloc = ii >> 6;
        int k0 = (ii & 63) * 2;
        int n = n0 + w * 16 + rloc;
        float2 v = make_float2(0.f, 0.f);
        if (n < N) {
            v = *(const float2*)(&emb[(size_t)zL[w * 16 + rloc] * HCH + k0]);
            *(float2*)(&h[(size_t)n * HCH + k0]) = v;
        }
        unsigned pk = pk2bf(v.x, v.y);
        int si = w * 2048 + (k0 >> 5) * 512 + (rloc + 16 * ((k0 >> 3) & 3)) * 8 + (k0 & 7);
        *(unsigned*)(&A3[si]) = pk;
    }
    int quad = lane >> 4, col = lane & 15;
    const bf16x8* B = (const bf16x8*)l1wp0;
    bf16x8 af[4];
#pragma unroll
    for (int kk = 0; kk < 4; kk++)
        af[kk] = *(const bf16x8*)(&A3[w * 2048 + kk * 512 + lane * 8]);
#pragma unroll
    for (int nt = 0; nt < 4; nt++) {
        floatx4 c = {0.f, 0.f, 0.f, 0.f};
#pragma unroll
        for (int kk = 0; kk < 4; kk++) c = MFMA(af[kk], B[(nt * 4 + kk) * 64 + lane], c);
        int f = nt * 16 + col;
#pragma unroll
        for (int reg = 0; reg < 4; reg++) {
            int n = n0 + w * 16 + quad * 4 + reg;
            if (n < N) xj[(size_t)n * FCH + f] = c[reg];
        }
    }
}

// ---------------------------------------------------------------------------
// Edge kernel R4: one block per 64-node dst bucket. Per edge (one thread):
// W = lerp(Wtab) ; msg = W*C*xj[src] ; ds_add into LDS tile ; direct store.
// ---------------------------------------------------------------------------
__global__ __launch_bounds__(256) void k_edge(
    const int4* __restrict__ edata, const float* __restrict__ xj,
    const float* __restrict__ Wt, const int* __restrict__ bstart,
    float* __restrict__ agg, int N)
{
    __shared__ float aggT[64 * 65];
    int t = threadIdx.x, b = blockIdx.x;
    for (int i = t; i < 64 * 65; i += 256) aggT[i] = 0.f;
    __syncthreads();

    int start = bstart[b], end = bstart[b + 1];
    int nb = b * 64;
    const float scale = (float)(TBL - 1) / DMAX;

    for (int e0 = start; e0 < end; e0 += 256) {
        int e = e0 + t;
        if (e < end) {
            int4 ed = edata[e];
            float d = __int_as_float(ed.z);
            float C = __int_as_float(ed.w);
            float u = d * scale;
            int i0 = (int)u;
            i0 = (i0 > TBL - 2) ? (TBL - 2) : i0;
            float fr = u - (float)i0;
            const float4* W0 = (const float4*)(Wt + (size_t)i0 * 64);
            const float4* X  = (const float4*)(xj + (size_t)ed.x * 64);
            float* ap = aggT + (ed.y - nb) * 65;
#pragma unroll
            for (int g = 0; g < 16; g++) {
                float4 w0 = W0[g];
                float4 w1 = W0[g + 16];     // next table row
                float4 x  = X[g];
                float m0 = (w0.x + fr * (w1.x - w0.x)) * C * x.x;
                float m1 = (w0.y + fr * (w1.y - w0.y)) * C * x.y;
                float m2 = (w0.z + fr * (w1.z - w0.z)) * C * x.z;
                float m3 = (w0.w + fr * (w1.w - w0.w)) * C * x.w;
                atomicAdd(ap + 4 * g + 0, m0);
                atomicAdd(ap + 4 * g + 1, m1);
                atomicAdd(ap + 4 * g + 2, m2);
                atomicAdd(ap + 4 * g + 3, m3);
            }
        }
    }
    __syncthreads();
    for (int i = t; i < 4096; i += 256) {
        int row = i >> 6, f = i & 63;
        int n = nb + row;
        if (n < N) agg[(size_t)n * FCH + f] = aggT[row * 65 + f];
    }
}

// ---------------------------------------------------------------------------
// Node update (layers 0,1): x=ssp(agg@l2w+b); x=x@lw+b; h+=x; xj=h@l1w[l+1]
// ---------------------------------------------------------------------------
__global__ __launch_bounds__(256) void k_update(
    const float* __restrict__ agg, const short* __restrict__ l2wp,
    const float* __restrict__ l2b, const short* __restrict__ lwp,
    const float* __restrict__ lb,  const short* __restrict__ l1wp_next,
    float* __restrict__ h, float* __restrict__ xj, int layer, int N)
{
    __shared__ __align__(16) short Aa[4096];
    __shared__ __align__(16) short A2[8192];
    __shared__ __align__(16) short A3[8192];
    int t = threadIdx.x, lane = t & 63, w = t >> 6;
    int n0 = blockIdx.x * 64;
#pragma unroll
    for (int m = 0; m < 8; m++) {
        int ii = lane + 64 * m;
        int rloc = ii >> 5;
        int k0 = (ii & 31) * 2;
        int n = n0 + w * 16 + rloc;
        float2 v = make_float2(0.f, 0.f);
        if (n < N) v = *(const float2*)(&agg[(size_t)n * FCH + k0]);
        unsigned pk = pk2bf(v.x, v.y);
        int si = w * 1024 + (k0 >> 5) * 512 + (rloc + 16 * ((k0 >> 3) & 3)) * 8 + (k0 & 7);
        *(unsigned*)(&Aa[si]) = pk;
    }
    int quad = lane >> 4, col = lane & 15;
    const bf16x8* Bl2 = (const bf16x8*)(l2wp + layer * 8192);
    const bf16x8* Blw = (const bf16x8*)(lwp + layer * 16384);
    const bf16x8* Bl1 = (const bf16x8*)l1wp_next;

    bf16x8 a0 = *(const bf16x8*)(&Aa[w * 1024 + lane * 8]);
    bf16x8 a1 = *(const bf16x8*)(&Aa[w * 1024 + 512 + lane * 8]);
#pragma unroll
    for (int nt = 0; nt < 8; nt++) {
        float bias = l2b[layer * HCH + nt * 16 + col];
        floatx4 c = {bias, bias, bias, bias};
        c = MFMA(a0, Bl2[(nt * 2 + 0) * 64 + lane], c);
        c = MFMA(a1, Bl2[(nt * 2 + 1) * 64 + lane], c);
        int f = nt * 16 + col;
        int si0 = w * 2048 + (f >> 5) * 512 + (16 * ((f >> 3) & 3)) * 8 + (f & 7);
#pragma unroll
        for (int reg = 0; reg < 4; reg++)
            A2[si0 + (quad * 4 + reg) * 8] = (short)f2bf(sspf(c[reg]));
    }
    bf16x8 af[4];
#pragma unroll
    for (int kk = 0; kk < 4; kk++)
        af[kk] = *(const bf16x8*)(&A2[w * 2048 + kk * 512 + lane * 8]);
#pragma unroll
    for (int nt = 0; nt < 8; nt++) {
        float bias = lb[layer * HCH + nt * 16 + col];
        floatx4 c = {bias, bias, bias, bias};
#pragma unroll
        for (int kk = 0; kk < 4; kk++) c = MFMA(af[kk], Blw[(nt * 4 + kk) * 64 + lane], c);
        int f = nt * 16 + col;
        int si0 = w * 2048 + (f >> 5) * 512 + (16 * ((f >> 3) & 3)) * 8 + (f & 7);
#pragma unroll
        for (int reg = 0; reg < 4; reg++) {
            int n = n0 + w * 16 + quad * 4 + reg;
            float hv = 0.f;
            if (n < N) {
                hv = h[(size_t)n * HCH + f] + c[reg];
                h[(size_t)n * HCH + f] = hv;
            }
            A3[si0 + (quad * 4 + reg) * 8] = (short)f2bf(hv);
        }
    }
#pragma unroll
    for (int kk = 0; kk < 4; kk++)
        af[kk] = *(const bf16x8*)(&A3[w * 2048 + kk * 512 + lane * 8]);
#pragma unroll
    for (int nt = 0; nt < 4; nt++) {
        floatx4 c = {0.f, 0.f, 0.f, 0.f};
#pragma unroll
        for (int kk = 0; kk < 4; kk++) c = MFMA(af[kk], Bl1[(nt * 4 + kk) * 64 + lane], c);
        int f = nt * 16 + col;
#pragma unroll
        for (int reg = 0; reg < 4; reg++) {
            int n = n0 + w * 16 + quad * 4 + reg;
            if (n < N) xj[(size_t)n * FCH + f] = c[reg];
        }
    }
}

// ---------------------------------------------------------------------------
// Final layer: node update + output MLP + per-graph atomic readout
// ---------------------------------------------------------------------------
__global__ __launch_bounds__(256) void k_final(
    const float* __restrict__ agg, const short* __restrict__ l2wp,
    const float* __restrict__ l2b, const short* __restrict__ lwp,
    const float* __restrict__ lb,  const short* __restrict__ ow1p,
    const float* __restrict__ ob1, const float* __restrict__ ow2,
    const float* __restrict__ ob2, const int* __restrict__ batch,
    const float* __restrict__ h, float* __restrict__ out, int layer, int N)
{
    __shared__ __align__(16) short Aa[4096];
    __shared__ __align__(16) short A2[8192];
    __shared__ __align__(16) short A3[8192];
    __shared__ float R[64 * 17];
    int t = threadIdx.x, lane = t & 63, w = t >> 6;
    int n0 = blockIdx.x * 64;
#pragma unroll
    for (int m = 0; m < 8; m++) {
        int ii = lane + 64 * m;
        int rloc = ii >> 5;
        int k0 = (ii & 31) * 2;
        int n = n0 + w * 16 + rloc;
        float2 v = make_float2(0.f, 0.f);
        if (n < N) v = *(const float2*)(&agg[(size_t)n * FCH + k0]);
        unsigned pk = pk2bf(v.x, v.y);
        int si = w * 1024 + (k0 >> 5) * 512 + (rloc + 16 * ((k0 >> 3) & 3)) * 8 + (k0 & 7);
        *(unsigned*)(&Aa[si]) = pk;
    }
    int quad = lane >> 4, col = lane & 15;
    const bf16x8* Bl2 = (const bf16x8*)(l2wp + layer * 8192);
    const bf16x8* Blw = (const bf16x8*)(lwp + layer * 16384);
    const bf16x8* Bow = (const bf16x8*)ow1p;

    bf16x8 a0 = *(const bf16x8*)(&Aa[w * 1024 + lane * 8]);
    bf16x8 a1 = *(const bf16x8*)(&Aa[w * 1024 + 512 + lane * 8]);
#pragma unroll
    for (int nt = 0; nt < 8; nt++) {
        float bias = l2b[layer * HCH + nt * 16 + col];
        floatx4 c = {bias, bias, bias, bias};
        c = MFMA(a0, Bl2[(nt * 2 + 0) * 64 + lane], c);
        c = MFMA(a1, Bl2[(nt * 2 + 1) * 64 + lane], c);
        int f = nt * 16 + col;
        int si0 = w * 2048 + (f >> 5) * 512 + (16 * ((f >> 3) & 3)) * 8 + (f & 7);
#pragma unroll
        for (int reg = 0; reg < 4; reg++)
            A2[si0 + (quad * 4 + reg) * 8] = (short)f2bf(sspf(c[reg]));
    }
    bf16x8 af[4];
#pragma unroll
    for (int kk = 0; kk < 4; kk++)
        af[kk] = *(const bf16x8*)(&A2[w * 2048 + kk * 512 + lane * 8]);
#pragma unroll
    for (int nt = 0; nt < 8; nt++) {
        float bias = lb[layer * HCH + nt * 16 + col];
        floatx4 c = {bias, bias, bias, bias};
#pragma unroll
        for (int kk = 0; kk < 4; kk++) c = MFMA(af[kk], Blw[(nt * 4 + kk) * 64 + lane], c);
        int f = nt * 16 + col;
        int si0 = w * 2048 + (f >> 5) * 512 + (16 * ((f >> 3) & 3)) * 8 + (f & 7);
#pragma unroll
        for (int reg = 0; reg < 4; reg++) {
            int n = n0 + w * 16 + quad * 4 + reg;
            float hv = 0.f;
            if (n < N) hv = h[(size_t)n * HCH + f] + c[reg];
            A3[si0 + (quad * 4 + reg) * 8] = (short)f2bf(hv);
        }
    }
#pragma unroll
    for (int kk = 0; kk < 4; kk++)
        af[kk] = *(const bf16x8*)(&A3[w * 2048 + kk * 512 + lane * 8]);
    float p[4] = {0.f, 0.f, 0.f, 0.f};
#pragma unroll
    for (int nt = 0; nt < 4; nt++) {
        float bias = ob1[nt * 16 + col];
        floatx4 c = {bias, bias, bias, bias};
#pragma unroll
        for (int kk = 0; kk < 4; kk++) c = MFMA(af[kk], Bow[(nt * 4 + kk) * 64 + lane], c);
        float w2 = ow2[nt * 16 + col];
#pragma unroll
        for (int reg = 0; reg < 4; reg++) p[reg] += sspf(c[reg]) * w2;
    }
#pragma unroll
    for (int reg = 0; reg < 4; reg++)
        R[(w * 16 + quad * 4 + reg) * 17 + col] = p[reg];
    __syncthreads();
    if (t < 64) {
        int n = n0 + t;
        if (n < N) {
            float v = ob2[0];
#pragma unroll
            for (int c2 = 0; c2 < 16; c2++) v += R[t * 17 + c2];
            unsafeAtomicAdd(&out[batch[n]], v);
        }
    }
}

// ---------------------------------------------------------------------------
extern "C" void kernel_launch(void* const* d_in, const int* in_sizes, int n_in,
                              void* d_out, int out_size, void* d_ws, size_t ws_size,
                              hipStream_t stream)
{
    const int*   z    = (const int*)d_in[0];
    const float* pos  = (const float*)d_in[1];
    const int*   batc = (const int*)d_in[2];
    const int*   ei   = (const int*)d_in[3];
    const float* emb  = (const float*)d_in[4];
    const float* mw1  = (const float*)d_in[5];
    const float* mb1  = (const float*)d_in[6];
    const float* mw2  = (const float*)d_in[7];
    const float* mb2  = (const float*)d_in[8];
    const float* l1w  = (const float*)d_in[9];
    const float* l2w  = (const float*)d_in[10];
    const float* l2b  = (const float*)d_in[11];
    const float* lw   = (const float*)d_in[12];
    const float* lb   = (const float*)d_in[13];
    const float* ow1  = (const float*)d_in[14];
    const float* ob1  = (const float*)d_in[15];
    const float* ow2  = (const float*)d_in[16];
    const float* ob2  = (const float*)d_in[17];
    float* out = (float*)d_out;

    int N = in_sizes[0];
    int E = in_sizes[3] / 2;
    int NBK = (N + 63) / 64;     // dst buckets of 64 nodes

    char* ws = (char*)d_ws;
    size_t off = 0;
    auto alloc = [&](size_t bytes) {
        void* p = ws + off;
        off = (off + bytes + 255) & ~(size_t)255;
        return p;
    };
    float* h      = (float*)alloc((size_t)N * HCH * 4);
    float* xj     = (float*)alloc((size_t)N * FCH * 4);
    float* agg    = (float*)alloc((size_t)N * FCH * 4);
    int4*  edata  = (int4*)alloc((size_t)E * 16);
    float* Wtab   = (float*)alloc((size_t)LN * TBL * 64 * 4);
    int*   hist   = (int*)alloc((size_t)NBK * 4);
    int*   cursor = (int*)alloc((size_t)NBK * 4);
    int*   bstart = (int*)alloc((size_t)(NBK + 1) * 4);
    short* l1wp   = (short*)alloc(LN * 8192 * 2);
    short* l2wp   = (short*)alloc(LN * 8192 * 2);
    short* lwp    = (short*)alloc(LN * 16384 * 2);
    short* ow1p   = (short*)alloc(8192 * 2);

    int EB256 = (E + 255) / 256;
    int NB = (N + 63) / 64;

    k_prep<<<32, 256, 0, stream>>>(l1w, l2w, lw, ow1, l1wp, l2wp, lwp, ow1p);
    k_wtab<<<(LN * TBL + 255) / 256, 256, 0, stream>>>(mw1, mb1, mw2, mb2, Wtab);
    hipMemsetAsync(hist, 0, (size_t)NBK * 4, stream);
    k_hist<<<EB256, 256, 0, stream>>>(ei, hist, E);
    k_scan<<<1, 1024, 0, stream>>>(hist, cursor, bstart, NBK);
    k_scatter2<<<EB256, 256, 0, stream>>>(ei, pos, cursor, edata, E);
    hipMemsetAsync(out, 0, (size_t)out_size * sizeof(float), stream);

    k_node0<<<NB, 256, 0, stream>>>(z, emb, l1wp, h, xj, N);
    for (int l = 0; l < LN; l++) {
        k_edge<<<NBK, 256, 0, stream>>>(edata, xj, Wtab + (size_t)l * TBL * 64,
                                        bstart, agg, N);
        if (l < LN - 1) {
            k_update<<<NB, 256, 0, stream>>>(agg, l2wp, l2b, lwp, lb,
                                             l1wp + (l + 1) * 8192, h, xj, l, N);
        } else {
            k_final<<<NB, 256, 0, stream>>>(agg, l2wp, l2b, lwp, lb, ow1p,
                                            ob1, ow2, ob2, batc, h, out, l, N);
        }
    }
}

// Round 5
// 719.676 us; speedup vs baseline: 4.5253x; 4.5253x over previous
//
#include <hip/hip_runtime.h>

// ---------------------------------------------------------------------------
// SchNet-style GNN on MI355X — R5.
// N=50000, E=1600000, H=128, F=64, G=50, L=3, NG=256.
// R5 = R2's sort+segmented-reduce aggregation  +  R4's W(d) lookup table.
//  - Wtab[l][tix][f] = W(d_tix)*C(d_tix) as bf16, TBL=4096 (nearest entry;
//    quantization error ~5e-4 << bf16 rounding already in the node path)
//  - edata = 8B/edge {src | tix<<17, dst}, exact dst counting sort
//  - k_edge: no MFMA, no barriers; 4 thr/edge gather+fma -> LDS msg tile ->
//    intra-wave segmented reduce -> global atomics at segment boundaries only
// Node GEMMs: bf16 MFMA fused per layer (unchanged from R3/R4).
// ---------------------------------------------------------------------------

typedef short bf16x8 __attribute__((ext_vector_type(8)));
typedef unsigned short ushort8 __attribute__((ext_vector_type(8)));
typedef float floatx4 __attribute__((ext_vector_type(4)));

#define HCH 128
#define FCH 64
#define GCH 50
#define LN  3
#define TBL 4096
#define DMAX 8.6603f     // pos in [0,5)^3 -> d <= 5*sqrt(3)

#define MFMA(a, b, c) __builtin_amdgcn_mfma_f32_16x16x32_bf16((a), (b), (c), 0, 0, 0)

__device__ __forceinline__ unsigned short f2bf(float x) {
    unsigned int u = __float_as_uint(x);
    unsigned int r = (u + 0x7FFFu + ((u >> 16) & 1u)) >> 16;
    return (unsigned short)r;
}

__device__ __forceinline__ unsigned pk2bf(float lo, float hi) {
    unsigned ulo = __float_as_uint(lo) + 0x8000u;
    unsigned uhi = __float_as_uint(hi) + 0x8000u;
    return __builtin_amdgcn_perm(uhi, ulo, 0x07060302u);
}

__device__ __forceinline__ float bf2f(unsigned short u) {
    return __uint_as_float((unsigned)u << 16);
}

__device__ __forceinline__ float sspf(float x) {
    float t = __expf(-fabsf(x));
    float l = __logf(1.f + t);
    return fmaxf(x, 0.f) + l - 0.69314718056f;
}

// ---------------------------------------------------------------------------
// frag fill for node-side MFMA weights (B-fragment order)
// ---------------------------------------------------------------------------
__device__ __forceinline__ void fill_frag(const float* __restrict__ src,
                                          short* __restrict__ dst,
                                          int K, int F, int Ksrc,
                                          int tid, int nthr)
{
    int kc = K >> 5;
    int total = (F >> 4) * kc * 512;
    for (int i = tid; i < total; i += nthr) {
        int j = i & 7;
        int lane = (i >> 3) & 63;
        int rest = i >> 9;
        int kk = rest % kc;
        int nt = rest / kc;
        int k = kk * 32 + ((lane >> 4) << 3) + j;
        int f = nt * 16 + (lane & 15);
        float v = (k < Ksrc) ? src[k * F + f] : 0.f;
        dst[i] = (short)f2bf(v);
    }
}

__global__ void k_prep(const float* __restrict__ l1w, const float* __restrict__ l2w,
                       const float* __restrict__ lw,  const float* __restrict__ ow1,
                       short* __restrict__ l1wp, short* __restrict__ l2wp,
                       short* __restrict__ lwp,  short* __restrict__ ow1p)
{
    int tid = blockIdx.x * blockDim.x + threadIdx.x;
    int nthr = gridDim.x * blockDim.x;
    for (int l = 0; l < LN; l++) {
        fill_frag(l1w + l * HCH * FCH, l1wp + l * 8192, 128, 64, 128, tid, nthr);
        fill_frag(l2w + l * FCH * HCH, l2wp + l * 8192, 64, 128, 64, tid, nthr);
        fill_frag(lw  + l * HCH * HCH, lwp  + l * 16384, 128, 128, 128, tid, nthr);
    }
    fill_frag(ow1, ow1p, 128, 64, 128, tid, nthr);
}

// ---------------------------------------------------------------------------
// Wtab[l][k][f] = (ssp(ea(d_k)@mw1+b1)@mw2+b2)[f] * C(d_k), bf16.
// One wave per table entry; LDS sh[] is same-wave produce/consume.
// ---------------------------------------------------------------------------
__global__ __launch_bounds__(64) void k_wtab(
    const float* __restrict__ mw1, const float* __restrict__ mb1,
    const float* __restrict__ mw2, const float* __restrict__ mb2,
    unsigned short* __restrict__ Wtb)
{
    __shared__ float sh[64];
    int blk = blockIdx.x;          // l*TBL + k
    int l = blk / TBL, k = blk - l * TBL;
    int f = threadIdx.x;
    float d = (float)k * (DMAX / (float)(TBL - 1));
    const float step = 10.f / 49.f;
    const float coeff = -0.5f / (step * step);

    float t1 = mb1[l * 64 + f];
    const float* w1 = mw1 + l * GCH * 64;
    for (int g = 0; g < GCH; g++) {
        float u = d - (float)g * step;
        t1 += __expf(coeff * u * u) * w1[g * 64 + f];
    }
    sh[f] = sspf(t1);              // one wave: program order suffices
    float acc = mb2[l * 64 + f];
    const float* w2 = mw2 + l * 64 * 64;
    for (int g = 0; g < 64; g++) acc += sh[g] * w2[g * 64 + f];
    float C = 0.5f * (__cosf(d * 0.31415926535897932f) + 1.f);
    Wtb[(size_t)blk * 64 + f] = f2bf(acc * C);
}

// ---------------------------------------------------------------------------
// Exact counting sort by dst: hist -> scan -> scatter (8B packed payload)
// ---------------------------------------------------------------------------
__global__ void k_hist(const int* __restrict__ ei, int* __restrict__ hist, int E)
{
    int e = blockIdx.x * blockDim.x + threadIdx.x;
    if (e < E) atomicAdd(&hist[ei[E + e]], 1);
}

__global__ __launch_bounds__(1024) void k_scan(const int* __restrict__ hist,
                                               int* __restrict__ cursor, int N)
{
    __shared__ int part[1024];
    int t = threadIdx.x;
    int b = t * 49;
    int s = 0;
    for (int i = 0; i < 49; i++) { int idx = b + i; if (idx < N) s += hist[idx]; }
    part[t] = s;
    __syncthreads();
    for (int off = 1; off < 1024; off <<= 1) {
        int v = (t >= off) ? part[t - off] : 0;
        __syncthreads();
        part[t] += v;
        __syncthreads();
    }
    int run = (t > 0) ? part[t - 1] : 0;
    for (int i = 0; i < 49; i++) {
        int idx = b + i;
        if (idx < N) { cursor[idx] = run; run += hist[idx]; }
    }
}

__global__ void k_scatter2(const int* __restrict__ ei, const float* __restrict__ pos,
                           int* __restrict__ cursor, int2* __restrict__ edata, int E)
{
    int e = blockIdx.x * blockDim.x + threadIdx.x;
    if (e >= E) return;
    int s = ei[e], d2 = ei[E + e];
    float dx = pos[s * 3 + 0] - pos[d2 * 3 + 0];
    float dy = pos[s * 3 + 1] - pos[d2 * 3 + 1];
    float dz = pos[s * 3 + 2] - pos[d2 * 3 + 2];
    float dist = sqrtf(dx * dx + dy * dy + dz * dz);
    int tix = (int)(dist * ((float)(TBL - 1) / DMAX) + 0.5f);
    tix = (tix > TBL - 1) ? (TBL - 1) : tix;
    int p = atomicAdd(&cursor[d2], 1);
    edata[p] = make_int2(s | (tix << 17), d2);
}

// ---------------------------------------------------------------------------
// k_node0: h = emb[z]; xj = h @ l1w[0]
// ---------------------------------------------------------------------------
__global__ __launch_bounds__(256) void k_node0(const int* __restrict__ z,
    const float* __restrict__ emb, const short* __restrict__ l1wp0,
    float* __restrict__ h, float* __restrict__ xj, int N)
{
    __shared__ __align__(16) short A3[8192];
    __shared__ int zL[64];
    int t = threadIdx.x, lane = t & 63, w = t >> 6;
    int n0 = blockIdx.x * 64;
    if (t < 64) { int n = n0 + t; zL[t] = (n < N) ? z[n] : 0; }
    __syncthreads();
#pragma unroll
    for (int m = 0; m < 16; m++) {
        int ii = lane + 64 * m;
        int rloc = ii >> 6;
        int k0 = (ii & 63) * 2;
        int n = n0 + w * 16 + rloc;
        float2 v = make_float2(0.f, 0.f);
        if (n < N) {
            v = *(const float2*)(&emb[(size_t)zL[w * 16 + rloc] * HCH + k0]);
            *(float2*)(&h[(size_t)n * HCH + k0]) = v;
        }
        unsigned pk = pk2bf(v.x, v.y);
        int si = w * 2048 + (k0 >> 5) * 512 + (rloc + 16 * ((k0 >> 3) & 3)) * 8 + (k0 & 7);
        *(unsigned*)(&A3[si]) = pk;
    }
    int quad = lane >> 4, col = lane & 15;
    const bf16x8* B = (const bf16x8*)l1wp0;
    bf16x8 af[4];
#pragma unroll
    for (int kk = 0; kk < 4; kk++)
        af[kk] = *(const bf16x8*)(&A3[w * 2048 + kk * 512 + lane * 8]);
#pragma unroll
    for (int nt = 0; nt < 4; nt++) {
        floatx4 c = {0.f, 0.f, 0.f, 0.f};
#pragma unroll
        for (int kk = 0; kk < 4; kk++) c = MFMA(af[kk], B[(nt * 4 + kk) * 64 + lane], c);
        int f = nt * 16 + col;
#pragma unroll
        for (int reg = 0; reg < 4; reg++) {
            int n = n0 + w * 16 + quad * 4 + reg;
            if (n < N) xj[(size_t)n * FCH + f] = c[reg];
        }
    }
}

// ---------------------------------------------------------------------------
// Edge kernel R5: 64 sorted edges/block, 4 thr/edge, no MFMA, no barriers.
// msg[e][f] = Wtab[tix][f] * xj[src][f]   (C folded into Wtab)
// -> LDS tile -> intra-wave segmented reduce -> boundary atomics.
// ---------------------------------------------------------------------------
__global__ __launch_bounds__(256) void k_edge(
    const int2* __restrict__ edata, const float* __restrict__ xj,
    const unsigned short* __restrict__ Wt,
    float* __restrict__ agg, int E)
{
    __shared__ float M[64 * 68];
    __shared__ int tD[64];

    int t = threadIdx.x, lane = t & 63, w = t >> 6;
    int r  = w * 16 + (lane >> 2);        // local edge row 0..63
    int fq = lane & 3;                    // 16-float chunk
    int eg = blockIdx.x * 64 + r;

    int2 ed = make_int2(0, -1);
    if (eg < E) ed = edata[eg];
    int src = ed.x & 0x1FFFF;
    int tix = ((unsigned)ed.x) >> 17;
    if (fq == 0) tD[r] = ed.y;

    const ushort8* Wr = (const ushort8*)(Wt + ((size_t)tix << 6) + fq * 16);
    const float4*  X  = (const float4*)(xj + ((size_t)src << 6) + fq * 16);
    ushort8 w0 = Wr[0];
    ushort8 w1 = Wr[1];
    float4 x0 = X[0], x1 = X[1], x2 = X[2], x3 = X[3];

    float* Mr = &M[r * 68 + fq * 16];
    float4 m;
    m.x = bf2f(w0[0]) * x0.x; m.y = bf2f(w0[1]) * x0.y;
    m.z = bf2f(w0[2]) * x0.z; m.w = bf2f(w0[3]) * x0.w;
    *(float4*)(Mr + 0) = m;
    m.x = bf2f(w0[4]) * x1.x; m.y = bf2f(w0[5]) * x1.y;
    m.z = bf2f(w0[6]) * x1.z; m.w = bf2f(w0[7]) * x1.w;
    *(float4*)(Mr + 4) = m;
    m.x = bf2f(w1[0]) * x2.x; m.y = bf2f(w1[1]) * x2.y;
    m.z = bf2f(w1[2]) * x2.z; m.w = bf2f(w1[3]) * x2.w;
    *(float4*)(Mr + 8) = m;
    m.x = bf2f(w1[4]) * x3.x; m.y = bf2f(w1[5]) * x3.y;
    m.z = bf2f(w1[6]) * x3.z; m.w = bf2f(w1[7]) * x3.w;
    *(float4*)(Mr + 12) = m;

    // intra-wave segmented reduce: lane = f, walk this wave's 16 sorted rows
    {
        int f = lane;
        int base = w * 16;
        float a = 0.f;
        int cur = tD[base];
#pragma unroll
        for (int i = 0; i < 16; i++) {
            int d2 = tD[base + i];
            if (d2 != cur) {
                if (cur >= 0) unsafeAtomicAdd(&agg[(size_t)cur * FCH + f], a);
                a = 0.f; cur = d2;
            }
            a += M[(base + i) * 68 + f];
        }
        if (cur >= 0) unsafeAtomicAdd(&agg[(size_t)cur * FCH + f], a);
    }
}

// ---------------------------------------------------------------------------
// Node update (layers 0,1): x=ssp(agg@l2w+b); x=x@lw+b; h+=x; xj=h@l1w[l+1]
// ---------------------------------------------------------------------------
__global__ __launch_bounds__(256) void k_update(
    const float* __restrict__ agg, const short* __restrict__ l2wp,
    const float* __restrict__ l2b, const short* __restrict__ lwp,
    const float* __restrict__ lb,  const short* __restrict__ l1wp_next,
    float* __restrict__ h, float* __restrict__ xj, int layer, int N)
{
    __shared__ __align__(16) short Aa[4096];
    __shared__ __align__(16) short A2[8192];
    __shared__ __align__(16) short A3[8192];
    int t = threadIdx.x, lane = t & 63, w = t >> 6;
    int n0 = blockIdx.x * 64;
#pragma unroll
    for (int m = 0; m < 8; m++) {
        int ii = lane + 64 * m;
        int rloc = ii >> 5;
        int k0 = (ii & 31) * 2;
        int n = n0 + w * 16 + rloc;
        float2 v = make_float2(0.f, 0.f);
        if (n < N) v = *(const float2*)(&agg[(size_t)n * FCH + k0]);
        unsigned pk = pk2bf(v.x, v.y);
        int si = w * 1024 + (k0 >> 5) * 512 + (rloc + 16 * ((k0 >> 3) & 3)) * 8 + (k0 & 7);
        *(unsigned*)(&Aa[si]) = pk;
    }
    int quad = lane >> 4, col = lane & 15;
    const bf16x8* Bl2 = (const bf16x8*)(l2wp + layer * 8192);
    const bf16x8* Blw = (const bf16x8*)(lwp + layer * 16384);
    const bf16x8* Bl1 = (const bf16x8*)l1wp_next;

    bf16x8 a0 = *(const bf16x8*)(&Aa[w * 1024 + lane * 8]);
    bf16x8 a1 = *(const bf16x8*)(&Aa[w * 1024 + 512 + lane * 8]);
#pragma unroll
    for (int nt = 0; nt < 8; nt++) {
        float bias = l2b[layer * HCH + nt * 16 + col];
        floatx4 c = {bias, bias, bias, bias};
        c = MFMA(a0, Bl2[(nt * 2 + 0) * 64 + lane], c);
        c = MFMA(a1, Bl2[(nt * 2 + 1) * 64 + lane], c);
        int f = nt * 16 + col;
        int si0 = w * 2048 + (f >> 5) * 512 + (16 * ((f >> 3) & 3)) * 8 + (f & 7);
#pragma unroll
        for (int reg = 0; reg < 4; reg++)
            A2[si0 + (quad * 4 + reg) * 8] = (short)f2bf(sspf(c[reg]));
    }
    bf16x8 af[4];
#pragma unroll
    for (int kk = 0; kk < 4; kk++)
        af[kk] = *(const bf16x8*)(&A2[w * 2048 + kk * 512 + lane * 8]);
#pragma unroll
    for (int nt = 0; nt < 8; nt++) {
        float bias = lb[layer * HCH + nt * 16 + col];
        floatx4 c = {bias, bias, bias, bias};
#pragma unroll
        for (int kk = 0; kk < 4; kk++) c = MFMA(af[kk], Blw[(nt * 4 + kk) * 64 + lane], c);
        int f = nt * 16 + col;
        int si0 = w * 2048 + (f >> 5) * 512 + (16 * ((f >> 3) & 3)) * 8 + (f & 7);
#pragma unroll
        for (int reg = 0; reg < 4; reg++) {
            int n = n0 + w * 16 + quad * 4 + reg;
            float hv = 0.f;
            if (n < N) {
                hv = h[(size_t)n * HCH + f] + c[reg];
                h[(size_t)n * HCH + f] = hv;
            }
            A3[si0 + (quad * 4 + reg) * 8] = (short)f2bf(hv);
        }
    }
#pragma unroll
    for (int kk = 0; kk < 4; kk++)
        af[kk] = *(const bf16x8*)(&A3[w * 2048 + kk * 512 + lane * 8]);
#pragma unroll
    for (int nt = 0; nt < 4; nt++) {
        floatx4 c = {0.f, 0.f, 0.f, 0.f};
#pragma unroll
        for (int kk = 0; kk < 4; kk++) c = MFMA(af[kk], Bl1[(nt * 4 + kk) * 64 + lane], c);
        int f = nt * 16 + col;
#pragma unroll
        for (int reg = 0; reg < 4; reg++) {
            int n = n0 + w * 16 + quad * 4 + reg;
            if (n < N) xj[(size_t)n * FCH + f] = c[reg];
        }
    }
}

// ---------------------------------------------------------------------------
// Final layer: node update + output MLP + per-graph atomic readout
// ---------------------------------------------------------------------------
__global__ __launch_bounds__(256) void k_final(
    const float* __restrict__ agg, const short* __restrict__ l2wp,
    const float* __restrict__ l2b, const short* __restrict__ lwp,
    const float* __restrict__ lb,  const short* __restrict__ ow1p,
    const float* __restrict__ ob1, const float* __restrict__ ow2,
    const float* __restrict__ ob2, const int* __restrict__ batch,
    const float* __restrict__ h, float* __restrict__ out, int layer, int N)
{
    __shared__ __align__(16) short Aa[4096];
    __shared__ __align__(16) short A2[8192];
    __shared__ __align__(16) short A3[8192];
    __shared__ float R[64 * 17];
    int t = threadIdx.x, lane = t & 63, w = t >> 6;
    int n0 = blockIdx.x * 64;
#pragma unroll
    for (int m = 0; m < 8; m++) {
        int ii = lane + 64 * m;
        int rloc = ii >> 5;
        int k0 = (ii & 31) * 2;
        int n = n0 + w * 16 + rloc;
        float2 v = make_float2(0.f, 0.f);
        if (n < N) v = *(const float2*)(&agg[(size_t)n * FCH + k0]);
        unsigned pk = pk2bf(v.x, v.y);
        int si = w * 1024 + (k0 >> 5) * 512 + (rloc + 16 * ((k0 >> 3) & 3)) * 8 + (k0 & 7);
        *(unsigned*)(&Aa[si]) = pk;
    }
    int quad = lane >> 4, col = lane & 15;
    const bf16x8* Bl2 = (const bf16x8*)(l2wp + layer * 8192);
    const bf16x8* Blw = (const bf16x8*)(lwp + layer * 16384);
    const bf16x8* Bow = (const bf16x8*)ow1p;

    bf16x8 a0 = *(const bf16x8*)(&Aa[w * 1024 + lane * 8]);
    bf16x8 a1 = *(const bf16x8*)(&Aa[w * 1024 + 512 + lane * 8]);
#pragma unroll
    for (int nt = 0; nt < 8; nt++) {
        float bias = l2b[layer * HCH + nt * 16 + col];
        floatx4 c = {bias, bias, bias, bias};
        c = MFMA(a0, Bl2[(nt * 2 + 0) * 64 + lane], c);
        c = MFMA(a1, Bl2[(nt * 2 + 1) * 64 + lane], c);
        int f = nt * 16 + col;
        int si0 = w * 2048 + (f >> 5) * 512 + (16 * ((f >> 3) & 3)) * 8 + (f & 7);
#pragma unroll
        for (int reg = 0; reg < 4; reg++)
            A2[si0 + (quad * 4 + reg) * 8] = (short)f2bf(sspf(c[reg]));
    }
    bf16x8 af[4];
#pragma unroll
    for (int kk = 0; kk < 4; kk++)
        af[kk] = *(const bf16x8*)(&A2[w * 2048 + kk * 512 + lane * 8]);
#pragma unroll
    for (int nt = 0; nt < 8; nt++) {
        float bias = lb[layer * HCH + nt * 16 + col];
        floatx4 c = {bias, bias, bias, bias};
#pragma unroll
        for (int kk = 0; kk < 4; kk++) c = MFMA(af[kk], Blw[(nt * 4 + kk) * 64 + lane], c);
        int f = nt * 16 + col;
        int si0 = w * 2048 + (f >> 5) * 512 + (16 * ((f >> 3) & 3)) * 8 + (f & 7);
#pragma unroll
        for (int reg = 0; reg < 4; reg++) {
            int n = n0 + w * 16 + quad * 4 + reg;
            float hv = 0.f;
            if (n < N) hv = h[(size_t)n * HCH + f] + c[reg];
            A3[si0 + (quad * 4 + reg) * 8] = (short)f2bf(hv);
        }
    }
#pragma unroll
    for (int kk = 0; kk < 4; kk++)
        af[kk] = *(const bf16x8*)(&A3[w * 2048 + kk * 512 + lane * 8]);
    float p[4] = {0.f, 0.f, 0.f, 0.f};
#pragma unroll
    for (int nt = 0; nt < 4; nt++) {
        float bias = ob1[nt * 16 + col];
        floatx4 c = {bias, bias, bias, bias};
#pragma unroll
        for (int kk = 0; kk < 4; kk++) c = MFMA(af[kk], Bow[(nt * 4 + kk) * 64 + lane], c);
        float w2 = ow2[nt * 16 + col];
#pragma unroll
        for (int reg = 0; reg < 4; reg++) p[reg] += sspf(c[reg]) * w2;
    }
#pragma unroll
    for (int reg = 0; reg < 4; reg++)
        R[(w * 16 + quad * 4 + reg) * 17 + col] = p[reg];
    __syncthreads();
    if (t < 64) {
        int n = n0 + t;
        if (n < N) {
            float v = ob2[0];
#pragma unroll
            for (int c2 = 0; c2 < 16; c2++) v += R[t * 17 + c2];
            unsafeAtomicAdd(&out[batch[n]], v);
        }
    }
}

// ---------------------------------------------------------------------------
extern "C" void kernel_launch(void* const* d_in, const int* in_sizes, int n_in,
                              void* d_out, int out_size, void* d_ws, size_t ws_size,
                              hipStream_t stream)
{
    const int*   z    = (const int*)d_in[0];
    const float* pos  = (const float*)d_in[1];
    const int*   batc = (const int*)d_in[2];
    const int*   ei   = (const int*)d_in[3];
    const float* emb  = (const float*)d_in[4];
    const float* mw1  = (const float*)d_in[5];
    const float* mb1  = (const float*)d_in[6];
    const float* mw2  = (const float*)d_in[7];
    const float* mb2  = (const float*)d_in[8];
    const float* l1w  = (const float*)d_in[9];
    const float* l2w  = (const float*)d_in[10];
    const float* l2b  = (const float*)d_in[11];
    const float* lw   = (const float*)d_in[12];
    const float* lb   = (const float*)d_in[13];
    const float* ow1  = (const float*)d_in[14];
    const float* ob1  = (const float*)d_in[15];
    const float* ow2  = (const float*)d_in[16];
    const float* ob2  = (const float*)d_in[17];
    float* out = (float*)d_out;

    int N = in_sizes[0];
    int E = in_sizes[3] / 2;

    char* ws = (char*)d_ws;
    size_t off = 0;
    auto alloc = [&](size_t bytes) {
        void* p = ws + off;
        off = (off + bytes + 255) & ~(size_t)255;
        return p;
    };
    float* h      = (float*)alloc((size_t)N * HCH * 4);
    float* xj     = (float*)alloc((size_t)N * FCH * 4);
    float* agg    = (float*)alloc((size_t)N * FCH * 4);
    int2*  edata  = (int2*)alloc((size_t)E * 8);
    unsigned short* Wtab = (unsigned short*)alloc((size_t)LN * TBL * 64 * 2);
    int*   hist   = (int*)alloc((size_t)N * 4);
    int*   cursor = (int*)alloc((size_t)N * 4);
    short* l1wp   = (short*)alloc(LN * 8192 * 2);
    short* l2wp   = (short*)alloc(LN * 8192 * 2);
    short* lwp    = (short*)alloc(LN * 16384 * 2);
    short* ow1p   = (short*)alloc(8192 * 2);

    int EB256 = (E + 255) / 256;
    int NB = (N + 63) / 64;
    int EB = (E + 63) / 64;

    k_prep<<<32, 256, 0, stream>>>(l1w, l2w, lw, ow1, l1wp, l2wp, lwp, ow1p);
    k_wtab<<<LN * TBL, 64, 0, stream>>>(mw1, mb1, mw2, mb2, Wtab);
    hipMemsetAsync(hist, 0, (size_t)N * 4, stream);
    k_hist<<<EB256, 256, 0, stream>>>(ei, hist, E);
    k_scan<<<1, 1024, 0, stream>>>(hist, cursor, N);
    k_scatter2<<<EB256, 256, 0, stream>>>(ei, pos, cursor, edata, E);
    hipMemsetAsync(out, 0, (size_t)out_size * sizeof(float), stream);

    k_node0<<<NB, 256, 0, stream>>>(z, emb, l1wp, h, xj, N);
    for (int l = 0; l < LN; l++) {
        hipMemsetAsync(agg, 0, (size_t)N * FCH * 4, stream);
        k_edge<<<EB, 256, 0, stream>>>(edata, xj, Wtab + (size_t)l * TBL * 64,
                                       agg, E);
        if (l < LN - 1) {
            k_update<<<NB, 256, 0, stream>>>(agg, l2wp, l2b, lwp, lb,
                                             l1wp + (l + 1) * 8192, h, xj, l, N);
        } else {
            k_final<<<NB, 256, 0, stream>>>(agg, l2wp, l2b, lwp, lb, ow1p,
                                            ob1, ow2, ob2, batc, h, out, l, N);
        }
    }
}

// Round 6
// 620.813 us; speedup vs baseline: 5.2460x; 1.1592x over previous
//
#include <hip/hip_runtime.h>

// ---------------------------------------------------------------------------
// SchNet-style GNN on MI355X — R6.
// R6 = R5 + (a) segmented-shuffle readout (atomics 50000 -> ~2500, kills the
// out[256] cacheline contention that made k_final 131us) + (b) single 16KB
// LDS arena in k_update/k_final (Aa/A2/A3 are per-wave sequential -> alias;
// occupancy 3 -> 7 blocks/CU).
// ---------------------------------------------------------------------------

typedef short bf16x8 __attribute__((ext_vector_type(8)));
typedef unsigned short ushort8 __attribute__((ext_vector_type(8)));
typedef float floatx4 __attribute__((ext_vector_type(4)));

#define HCH 128
#define FCH 64
#define GCH 50
#define LN  3
#define TBL 4096
#define DMAX 8.6603f     // pos in [0,5)^3 -> d <= 5*sqrt(3)

#define MFMA(a, b, c) __builtin_amdgcn_mfma_f32_16x16x32_bf16((a), (b), (c), 0, 0, 0)

__device__ __forceinline__ unsigned short f2bf(float x) {
    unsigned int u = __float_as_uint(x);
    unsigned int r = (u + 0x7FFFu + ((u >> 16) & 1u)) >> 16;
    return (unsigned short)r;
}

__device__ __forceinline__ unsigned pk2bf(float lo, float hi) {
    unsigned ulo = __float_as_uint(lo) + 0x8000u;
    unsigned uhi = __float_as_uint(hi) + 0x8000u;
    return __builtin_amdgcn_perm(uhi, ulo, 0x07060302u);
}

__device__ __forceinline__ float bf2f(unsigned short u) {
    return __uint_as_float((unsigned)u << 16);
}

__device__ __forceinline__ float sspf(float x) {
    float t = __expf(-fabsf(x));
    float l = __logf(1.f + t);
    return fmaxf(x, 0.f) + l - 0.69314718056f;
}

// ---------------------------------------------------------------------------
// frag fill for node-side MFMA weights (B-fragment order)
// ---------------------------------------------------------------------------
__device__ __forceinline__ void fill_frag(const float* __restrict__ src,
                                          short* __restrict__ dst,
                                          int K, int F, int Ksrc,
                                          int tid, int nthr)
{
    int kc = K >> 5;
    int total = (F >> 4) * kc * 512;
    for (int i = tid; i < total; i += nthr) {
        int j = i & 7;
        int lane = (i >> 3) & 63;
        int rest = i >> 9;
        int kk = rest % kc;
        int nt = rest / kc;
        int k = kk * 32 + ((lane >> 4) << 3) + j;
        int f = nt * 16 + (lane & 15);
        float v = (k < Ksrc) ? src[k * F + f] : 0.f;
        dst[i] = (short)f2bf(v);
    }
}

__global__ void k_prep(const float* __restrict__ l1w, const float* __restrict__ l2w,
                       const float* __restrict__ lw,  const float* __restrict__ ow1,
                       short* __restrict__ l1wp, short* __restrict__ l2wp,
                       short* __restrict__ lwp,  short* __restrict__ ow1p)
{
    int tid = blockIdx.x * blockDim.x + threadIdx.x;
    int nthr = gridDim.x * blockDim.x;
    for (int l = 0; l < LN; l++) {
        fill_frag(l1w + l * HCH * FCH, l1wp + l * 8192, 128, 64, 128, tid, nthr);
        fill_frag(l2w + l * FCH * HCH, l2wp + l * 8192, 64, 128, 64, tid, nthr);
        fill_frag(lw  + l * HCH * HCH, lwp  + l * 16384, 128, 128, 128, tid, nthr);
    }
    fill_frag(ow1, ow1p, 128, 64, 128, tid, nthr);
}

// ---------------------------------------------------------------------------
// Wtab[l][k][f] = (ssp(ea(d_k)@mw1+b1)@mw2+b2)[f] * C(d_k), bf16.
// ---------------------------------------------------------------------------
__global__ __launch_bounds__(64) void k_wtab(
    const float* __restrict__ mw1, const float* __restrict__ mb1,
    const float* __restrict__ mw2, const float* __restrict__ mb2,
    unsigned short* __restrict__ Wtb)
{
    __shared__ float sh[64];
    int blk = blockIdx.x;          // l*TBL + k
    int l = blk / TBL, k = blk - l * TBL;
    int f = threadIdx.x;
    float d = (float)k * (DMAX / (float)(TBL - 1));
    const float step = 10.f / 49.f;
    const float coeff = -0.5f / (step * step);

    float t1 = mb1[l * 64 + f];
    const float* w1 = mw1 + l * GCH * 64;
    for (int g = 0; g < GCH; g++) {
        float u = d - (float)g * step;
        t1 += __expf(coeff * u * u) * w1[g * 64 + f];
    }
    sh[f] = sspf(t1);              // one wave: program order suffices
    float acc = mb2[l * 64 + f];
    const float* w2 = mw2 + l * 64 * 64;
    for (int g = 0; g < 64; g++) acc += sh[g] * w2[g * 64 + f];
    float C = 0.5f * (__cosf(d * 0.31415926535897932f) + 1.f);
    Wtb[(size_t)blk * 64 + f] = f2bf(acc * C);
}

// ---------------------------------------------------------------------------
// Exact counting sort by dst: hist -> scan -> scatter (8B packed payload)
// ---------------------------------------------------------------------------
__global__ void k_hist(const int* __restrict__ ei, int* __restrict__ hist, int E)
{
    int e = blockIdx.x * blockDim.x + threadIdx.x;
    if (e < E) atomicAdd(&hist[ei[E + e]], 1);
}

__global__ __launch_bounds__(1024) void k_scan(const int* __restrict__ hist,
                                               int* __restrict__ cursor, int N)
{
    __shared__ int part[1024];
    int t = threadIdx.x;
    int b = t * 49;
    int s = 0;
    for (int i = 0; i < 49; i++) { int idx = b + i; if (idx < N) s += hist[idx]; }
    part[t] = s;
    __syncthreads();
    for (int off = 1; off < 1024; off <<= 1) {
        int v = (t >= off) ? part[t - off] : 0;
        __syncthreads();
        part[t] += v;
        __syncthreads();
    }
    int run = (t > 0) ? part[t - 1] : 0;
    for (int i = 0; i < 49; i++) {
        int idx = b + i;
        if (idx < N) { cursor[idx] = run; run += hist[idx]; }
    }
}

__global__ void k_scatter2(const int* __restrict__ ei, const float* __restrict__ pos,
                           int* __restrict__ cursor, int2* __restrict__ edata, int E)
{
    int e = blockIdx.x * blockDim.x + threadIdx.x;
    if (e >= E) return;
    int s = ei[e], d2 = ei[E + e];
    float dx = pos[s * 3 + 0] - pos[d2 * 3 + 0];
    float dy = pos[s * 3 + 1] - pos[d2 * 3 + 1];
    float dz = pos[s * 3 + 2] - pos[d2 * 3 + 2];
    float dist = sqrtf(dx * dx + dy * dy + dz * dz);
    int tix = (int)(dist * ((float)(TBL - 1) / DMAX) + 0.5f);
    tix = (tix > TBL - 1) ? (TBL - 1) : tix;
    int p = atomicAdd(&cursor[d2], 1);
    edata[p] = make_int2(s | (tix << 17), d2);
}

// ---------------------------------------------------------------------------
// k_node0: h = emb[z]; xj = h @ l1w[0]
// ---------------------------------------------------------------------------
__global__ __launch_bounds__(256) void k_node0(const int* __restrict__ z,
    const float* __restrict__ emb, const short* __restrict__ l1wp0,
    float* __restrict__ h, float* __restrict__ xj, int N)
{
    __shared__ __align__(16) short A3[8192];
    __shared__ int zL[64];
    int t = threadIdx.x, lane = t & 63, w = t >> 6;
    int n0 = blockIdx.x * 64;
    if (t < 64) { int n = n0 + t; zL[t] = (n < N) ? z[n] : 0; }
    __syncthreads();
#pragma unroll
    for (int m = 0; m < 16; m++) {
        int ii = lane + 64 * m;
        int rloc = ii >> 6;
        int k0 = (ii & 63) * 2;
        int n = n0 + w * 16 + rloc;
        float2 v = make_float2(0.f, 0.f);
        if (n < N) {
            v = *(const float2*)(&emb[(size_t)zL[w * 16 + rloc] * HCH + k0]);
            *(float2*)(&h[(size_t)n * HCH + k0]) = v;
        }
        unsigned pk = pk2bf(v.x, v.y);
        int si = w * 2048 + (k0 >> 5) * 512 + (rloc + 16 * ((k0 >> 3) & 3)) * 8 + (k0 & 7);
        *(unsigned*)(&A3[si]) = pk;
    }
    int quad = lane >> 4, col = lane & 15;
    const bf16x8* B = (const bf16x8*)l1wp0;
    bf16x8 af[4];
#pragma unroll
    for (int kk = 0; kk < 4; kk++)
        af[kk] = *(const bf16x8*)(&A3[w * 2048 + kk * 512 + lane * 8]);
#pragma unroll
    for (int nt = 0; nt < 4; nt++) {
        floatx4 c = {0.f, 0.f, 0.f, 0.f};
#pragma unroll
        for (int kk = 0; kk < 4; kk++) c = MFMA(af[kk], B[(nt * 4 + kk) * 64 + lane], c);
        int f = nt * 16 + col;
#pragma unroll
        for (int reg = 0; reg < 4; reg++) {
            int n = n0 + w * 16 + quad * 4 + reg;
            if (n < N) xj[(size_t)n * FCH + f] = c[reg];
        }
    }
}

// ---------------------------------------------------------------------------
// Edge kernel (unchanged from R5): 64 sorted edges/block, 4 thr/edge.
// ---------------------------------------------------------------------------
__global__ __launch_bounds__(256) void k_edge(
    const int2* __restrict__ edata, const float* __restrict__ xj,
    const unsigned short* __restrict__ Wt,
    float* __restrict__ agg, int E)
{
    __shared__ float M[64 * 68];
    __shared__ int tD[64];

    int t = threadIdx.x, lane = t & 63, w = t >> 6;
    int r  = w * 16 + (lane >> 2);
    int fq = lane & 3;
    int eg = blockIdx.x * 64 + r;

    int2 ed = make_int2(0, -1);
    if (eg < E) ed = edata[eg];
    int src = ed.x & 0x1FFFF;
    int tix = ((unsigned)ed.x) >> 17;
    if (fq == 0) tD[r] = ed.y;

    const ushort8* Wr = (const ushort8*)(Wt + ((size_t)tix << 6) + fq * 16);
    const float4*  X  = (const float4*)(xj + ((size_t)src << 6) + fq * 16);
    ushort8 w0 = Wr[0];
    ushort8 w1 = Wr[1];
    float4 x0 = X[0], x1 = X[1], x2 = X[2], x3 = X[3];

    float* Mr = &M[r * 68 + fq * 16];
    float4 m;
    m.x = bf2f(w0[0]) * x0.x; m.y = bf2f(w0[1]) * x0.y;
    m.z = bf2f(w0[2]) * x0.z; m.w = bf2f(w0[3]) * x0.w;
    *(float4*)(Mr + 0) = m;
    m.x = bf2f(w0[4]) * x1.x; m.y = bf2f(w0[5]) * x1.y;
    m.z = bf2f(w0[6]) * x1.z; m.w = bf2f(w0[7]) * x1.w;
    *(float4*)(Mr + 4) = m;
    m.x = bf2f(w1[0]) * x2.x; m.y = bf2f(w1[1]) * x2.y;
    m.z = bf2f(w1[2]) * x2.z; m.w = bf2f(w1[3]) * x2.w;
    *(float4*)(Mr + 8) = m;
    m.x = bf2f(w1[4]) * x3.x; m.y = bf2f(w1[5]) * x3.y;
    m.z = bf2f(w1[6]) * x3.z; m.w = bf2f(w1[7]) * x3.w;
    *(float4*)(Mr + 12) = m;

    {
        int f = lane;
        int base = w * 16;
        float a = 0.f;
        int cur = tD[base];
#pragma unroll
        for (int i = 0; i < 16; i++) {
            int d2 = tD[base + i];
            if (d2 != cur) {
                if (cur >= 0) unsafeAtomicAdd(&agg[(size_t)cur * FCH + f], a);
                a = 0.f; cur = d2;
            }
            a += M[(base + i) * 68 + f];
        }
        if (cur >= 0) unsafeAtomicAdd(&agg[(size_t)cur * FCH + f], a);
    }
}

// ---------------------------------------------------------------------------
// Node update (layers 0,1): single 16KB per-block arena (per-wave 2048 shorts,
// staged/consumed strictly in program order -> Aa/A2/A3 alias safely).
// ---------------------------------------------------------------------------
__global__ __launch_bounds__(256) void k_update(
    const float* __restrict__ agg, const short* __restrict__ l2wp,
    const float* __restrict__ l2b, const short* __restrict__ lwp,
    const float* __restrict__ lb,  const short* __restrict__ l1wp_next,
    float* __restrict__ h, float* __restrict__ xj, int layer, int N)
{
    __shared__ __align__(16) short AR[8192];
    int t = threadIdx.x, lane = t & 63, w = t >> 6;
    int n0 = blockIdx.x * 64;
    short* WR = &AR[w * 2048];
    // stage agg (K=64) into arena
#pragma unroll
    for (int m = 0; m < 8; m++) {
        int ii = lane + 64 * m;
        int rloc = ii >> 5;
        int k0 = (ii & 31) * 2;
        int n = n0 + w * 16 + rloc;
        float2 v = make_float2(0.f, 0.f);
        if (n < N) v = *(const float2*)(&agg[(size_t)n * FCH + k0]);
        unsigned pk = pk2bf(v.x, v.y);
        int si = (k0 >> 5) * 512 + (rloc + 16 * ((k0 >> 3) & 3)) * 8 + (k0 & 7);
        *(unsigned*)(&WR[si]) = pk;
    }
    int quad = lane >> 4, col = lane & 15;
    const bf16x8* Bl2 = (const bf16x8*)(l2wp + layer * 8192);
    const bf16x8* Blw = (const bf16x8*)(lwp + layer * 16384);
    const bf16x8* Bl1 = (const bf16x8*)l1wp_next;

    bf16x8 a0 = *(const bf16x8*)(&WR[lane * 8]);
    bf16x8 a1 = *(const bf16x8*)(&WR[512 + lane * 8]);
    // GEMM1: ssp(agg@l2w+b) -> arena (overwrites staged agg, already in regs)
#pragma unroll
    for (int nt = 0; nt < 8; nt++) {
        float bias = l2b[layer * HCH + nt * 16 + col];
        floatx4 c = {bias, bias, bias, bias};
        c = MFMA(a0, Bl2[(nt * 2 + 0) * 64 + lane], c);
        c = MFMA(a1, Bl2[(nt * 2 + 1) * 64 + lane], c);
        int f = nt * 16 + col;
        int si0 = (f >> 5) * 512 + (16 * ((f >> 3) & 3)) * 8 + (f & 7);
#pragma unroll
        for (int reg = 0; reg < 4; reg++)
            WR[si0 + (quad * 4 + reg) * 8] = (short)f2bf(sspf(c[reg]));
    }
    bf16x8 af[4];
#pragma unroll
    for (int kk = 0; kk < 4; kk++)
        af[kk] = *(const bf16x8*)(&WR[kk * 512 + lane * 8]);
    // GEMM2: x@lw+b ; residual -> h, arena
#pragma unroll
    for (int nt = 0; nt < 8; nt++) {
        float bias = lb[layer * HCH + nt * 16 + col];
        floatx4 c = {bias, bias, bias, bias};
#pragma unroll
        for (int kk = 0; kk < 4; kk++) c = MFMA(af[kk], Blw[(nt * 4 + kk) * 64 + lane], c);
        int f = nt * 16 + col;
        int si0 = (f >> 5) * 512 + (16 * ((f >> 3) & 3)) * 8 + (f & 7);
#pragma unroll
        for (int reg = 0; reg < 4; reg++) {
            int n = n0 + w * 16 + quad * 4 + reg;
            float hv = 0.f;
            if (n < N) {
                hv = h[(size_t)n * HCH + f] + c[reg];
                h[(size_t)n * HCH + f] = hv;
            }
            WR[si0 + (quad * 4 + reg) * 8] = (short)f2bf(hv);
        }
    }
    // GEMM3: xj = h_new @ l1w[layer+1]
#pragma unroll
    for (int kk = 0; kk < 4; kk++)
        af[kk] = *(const bf16x8*)(&WR[kk * 512 + lane * 8]);
#pragma unroll
    for (int nt = 0; nt < 4; nt++) {
        floatx4 c = {0.f, 0.f, 0.f, 0.f};
#pragma unroll
        for (int kk = 0; kk < 4; kk++) c = MFMA(af[kk], Bl1[(nt * 4 + kk) * 64 + lane], c);
        int f = nt * 16 + col;
#pragma unroll
        for (int reg = 0; reg < 4; reg++) {
            int n = n0 + w * 16 + quad * 4 + reg;
            if (n < N) xj[(size_t)n * FCH + f] = c[reg];
        }
    }
}

// ---------------------------------------------------------------------------
// Final layer: node update + output MLP + segmented-shuffle readout.
// batch is sorted -> a 64-node block spans ~2-3 graphs; only segment heads
// issue atomics (total ~2500 instead of 50000).
// ---------------------------------------------------------------------------
__global__ __launch_bounds__(256) void k_final(
    const float* __restrict__ agg, const short* __restrict__ l2wp,
    const float* __restrict__ l2b, const short* __restrict__ lwp,
    const float* __restrict__ lb,  const short* __restrict__ ow1p,
    const float* __restrict__ ob1, const float* __restrict__ ow2,
    const float* __restrict__ ob2, const int* __restrict__ batch,
    const float* __restrict__ h, float* __restrict__ out, int layer, int N)
{
    __shared__ __align__(16) short AR[8192];
    __shared__ float R[64 * 17];
    int t = threadIdx.x, lane = t & 63, w = t >> 6;
    int n0 = blockIdx.x * 64;
    short* WR = &AR[w * 2048];
#pragma unroll
    for (int m = 0; m < 8; m++) {
        int ii = lane + 64 * m;
        int rloc = ii >> 5;
        int k0 = (ii & 31) * 2;
        int n = n0 + w * 16 + rloc;
        float2 v = make_float2(0.f, 0.f);
        if (n < N) v = *(const float2*)(&agg[(size_t)n * FCH + k0]);
        unsigned pk = pk2bf(v.x, v.y);
        int si = (k0 >> 5) * 512 + (rloc + 16 * ((k0 >> 3) & 3)) * 8 + (k0 & 7);
        *(unsigned*)(&WR[si]) = pk;
    }
    int quad = lane >> 4, col = lane & 15;
    const bf16x8* Bl2 = (const bf16x8*)(l2wp + layer * 8192);
    const bf16x8* Blw = (const bf16x8*)(lwp + layer * 16384);
    const bf16x8* Bow = (const bf16x8*)ow1p;

    bf16x8 a0 = *(const bf16x8*)(&WR[lane * 8]);
    bf16x8 a1 = *(const bf16x8*)(&WR[512 + lane * 8]);
#pragma unroll
    for (int nt = 0; nt < 8; nt++) {
        float bias = l2b[layer * HCH + nt * 16 + col];
        floatx4 c = {bias, bias, bias, bias};
        c = MFMA(a0, Bl2[(nt * 2 + 0) * 64 + lane], c);
        c = MFMA(a1, Bl2[(nt * 2 + 1) * 64 + lane], c);
        int f = nt * 16 + col;
        int si0 = (f >> 5) * 512 + (16 * ((f >> 3) & 3)) * 8 + (f & 7);
#pragma unroll
        for (int reg = 0; reg < 4; reg++)
            WR[si0 + (quad * 4 + reg) * 8] = (short)f2bf(sspf(c[reg]));
    }
    bf16x8 af[4];
#pragma unroll
    for (int kk = 0; kk < 4; kk++)
        af[kk] = *(const bf16x8*)(&WR[kk * 512 + lane * 8]);
#pragma unroll
    for (int nt = 0; nt < 8; nt++) {
        float bias = lb[layer * HCH + nt * 16 + col];
        floatx4 c = {bias, bias, bias, bias};
#pragma unroll
        for (int kk = 0; kk < 4; kk++) c = MFMA(af[kk], Blw[(nt * 4 + kk) * 64 + lane], c);
        int f = nt * 16 + col;
        int si0 = (f >> 5) * 512 + (16 * ((f >> 3) & 3)) * 8 + (f & 7);
#pragma unroll
        for (int reg = 0; reg < 4; reg++) {
            int n = n0 + w * 16 + quad * 4 + reg;
            float hv = 0.f;
            if (n < N) hv = h[(size_t)n * HCH + f] + c[reg];
            WR[si0 + (quad * 4 + reg) * 8] = (short)f2bf(hv);
        }
    }
#pragma unroll
    for (int kk = 0; kk < 4; kk++)
        af[kk] = *(const bf16x8*)(&WR[kk * 512 + lane * 8]);
    float p[4] = {0.f, 0.f, 0.f, 0.f};
#pragma unroll
    for (int nt = 0; nt < 4; nt++) {
        float bias = ob1[nt * 16 + col];
        floatx4 c = {bias, bias, bias, bias};
#pragma unroll
        for (int kk = 0; kk < 4; kk++) c = MFMA(af[kk], Bow[(nt * 4 + kk) * 64 + lane], c);
        float w2 = ow2[nt * 16 + col];
#pragma unroll
        for (int reg = 0; reg < 4; reg++) p[reg] += sspf(c[reg]) * w2;
    }
#pragma unroll
    for (int reg = 0; reg < 4; reg++)
        R[(w * 16 + quad * 4 + reg) * 17 + col] = p[reg];
    __syncthreads();
    if (t < 64) {
        int n = n0 + t;
        float v = 0.f;
        int g = -1;
        if (n < N) {
            v = ob2[0];
#pragma unroll
            for (int c2 = 0; c2 < 16; c2++) v += R[t * 17 + c2];
            g = batch[n];
        }
        // segmented suffix reduction over 64 sorted (g,v); heads do atomics
#pragma unroll
        for (int off2 = 1; off2 < 64; off2 <<= 1) {
            float vv = __shfl_down(v, off2, 64);
            int gg = __shfl_down(g, off2, 64);
            if (lane + off2 < 64 && gg == g) v += vv;
        }
        int gp = __shfl_up(g, 1, 64);
        bool head = (lane == 0) || (g != gp);
        if (head && g >= 0) unsafeAtomicAdd(&out[g], v);
    }
}

// ---------------------------------------------------------------------------
extern "C" void kernel_launch(void* const* d_in, const int* in_sizes, int n_in,
                              void* d_out, int out_size, void* d_ws, size_t ws_size,
                              hipStream_t stream)
{
    const int*   z    = (const int*)d_in[0];
    const float* pos  = (const float*)d_in[1];
    const int*   batc = (const int*)d_in[2];
    const int*   ei   = (const int*)d_in[3];
    const float* emb  = (const float*)d_in[4];
    const float* mw1  = (const float*)d_in[5];
    const float* mb1  = (const float*)d_in[6];
    const float* mw2  = (const float*)d_in[7];
    const float* mb2  = (const float*)d_in[8];
    const float* l1w  = (const float*)d_in[9];
    const float* l2w  = (const float*)d_in[10];
    const float* l2b  = (const float*)d_in[11];
    const float* lw   = (const float*)d_in[12];
    const float* lb   = (const float*)d_in[13];
    const float* ow1  = (const float*)d_in[14];
    const float* ob1  = (const float*)d_in[15];
    const float* ow2  = (const float*)d_in[16];
    const float* ob2  = (const float*)d_in[17];
    float* out = (float*)d_out;

    int N = in_sizes[0];
    int E = in_sizes[3] / 2;

    char* ws = (char*)d_ws;
    size_t off = 0;
    auto alloc = [&](size_t bytes) {
        void* p = ws + off;
        off = (off + bytes + 255) & ~(size_t)255;
        return p;
    };
    float* h      = (float*)alloc((size_t)N * HCH * 4);
    float* xj     = (float*)alloc((size_t)N * FCH * 4);
    float* agg    = (float*)alloc((size_t)N * FCH * 4);
    int2*  edata  = (int2*)alloc((size_t)E * 8);
    unsigned short* Wtab = (unsigned short*)alloc((size_t)LN * TBL * 64 * 2);
    int*   hist   = (int*)alloc((size_t)N * 4);
    int*   cursor = (int*)alloc((size_t)N * 4);
    short* l1wp   = (short*)alloc(LN * 8192 * 2);
    short* l2wp   = (short*)alloc(LN * 8192 * 2);
    short* lwp    = (short*)alloc(LN * 16384 * 2);
    short* ow1p   = (short*)alloc(8192 * 2);

    int EB256 = (E + 255) / 256;
    int NB = (N + 63) / 64;
    int EB = (E + 63) / 64;

    k_prep<<<32, 256, 0, stream>>>(l1w, l2w, lw, ow1, l1wp, l2wp, lwp, ow1p);
    k_wtab<<<LN * TBL, 64, 0, stream>>>(mw1, mb1, mw2, mb2, Wtab);
    hipMemsetAsync(hist, 0, (size_t)N * 4, stream);
    k_hist<<<EB256, 256, 0, stream>>>(ei, hist, E);
    k_scan<<<1, 1024, 0, stream>>>(hist, cursor, N);
    k_scatter2<<<EB256, 256, 0, stream>>>(ei, pos, cursor, edata, E);
    hipMemsetAsync(out, 0, (size_t)out_size * sizeof(float), stream);

    k_node0<<<NB, 256, 0, stream>>>(z, emb, l1wp, h, xj, N);
    for (int l = 0; l < LN; l++) {
        hipMemsetAsync(agg, 0, (size_t)N * FCH * 4, stream);
        k_edge<<<EB, 256, 0, stream>>>(edata, xj, Wtab + (size_t)l * TBL * 64,
                                       agg, E);
        if (l < LN - 1) {
            k_update<<<NB, 256, 0, stream>>>(agg, l2wp, l2b, lwp, lb,
                                             l1wp + (l + 1) * 8192, h, xj, l, N);
        } else {
            k_final<<<NB, 256, 0, stream>>>(agg, l2wp, l2b, lwp, lb, ow1p,
                                            ob1, ow2, ob2, batc, h, out, l, N);
        }
    }
}